// Round 7
// baseline (154.615 us; speedup 1.0000x reference)
//
#include <hip/hip_runtime.h>

// R7 = R6 + stage-2 wave remap: each wave owns 2 ntiles x ALL 4 mtiles.
//  - B-fragments (LDS b128, the dominant LDS-pipe load) read once per block
//    instead of 4x: 504 -> 144 reads/block. A-fragments (global, L2-resident)
//    read 4x more on the idle VMEM pipe.
//  - stage-1 pool folding branch-free (row array + v_max3).
// LDS 29952 B -> 5 blocks/CU.

typedef __attribute__((ext_vector_type(8))) short short8;   // 8 x bf16 (4 VGPRs)
typedef __attribute__((ext_vector_type(4))) float f32x4;

__device__ inline short f2bf(float f) {   // fp32 -> bf16, round-to-nearest-even
    union { float f; unsigned u; } v; v.f = f;
    unsigned r = (v.u + 0x7FFFu + ((v.u >> 16) & 1u)) >> 16;
    return (short)r;
}

// w2r[s][cout][cin] (bf16), s = ky*3+kx: MFMA A-fragments contiguous in cin.
__global__ __launch_bounds__(256) void prep_w2(const float* __restrict__ w2,
                                               short* __restrict__ w2r) {
    int i = blockIdx.x * 256 + threadIdx.x;      // 9*64*64 = 36864
    if (i >= 36864) return;
    int s = i >> 12, cout = (i >> 6) & 63, cin = i & 63;
    w2r[i] = f2bf(w2[cout * 576 + cin * 9 + s]);
}

__global__ __launch_bounds__(256) void convnet_fused(
    const float* __restrict__ x,   // [B,1,28,28]
    const float* __restrict__ w1,  // [64,1,3,3]
    const float* __restrict__ b1,  // [64]
    const short* __restrict__ w2r, // [9][64][64] bf16
    const float* __restrict__ b2,  // [64]
    const float* __restrict__ w3,  // [10,64,4,4]
    const float* __restrict__ b3,  // [10]
    float* __restrict__ out)       // [B,10]
{
    // Overlays (floats):
    //   [0..5184)    h1t bf16 [144 pos][72]    }-> cbuf fp32 [64][101] = [0..6464)
    //   [5184..5968) img 28x28                 }   (h1t & img dead by cbuf write)
    //   [6464..7488) h2t fp32 [16 pos][64 cin]
    //   [0..160)     stage-3 partials (cbuf dead)
    __shared__ float lds_f[7488];                // 29952 B
    short* h1t  = (short*)lds_f;
    float* img  = lds_f + 5184;
    float* cbuf = lds_f;
    float* h2t  = lds_f + 6464;
    float* prt  = lds_f;

    const int n_img = blockIdx.x;
    const int t = threadIdx.x;
    const int c = t >> 2;        // 0..63
    const int q = t & 3;         // quadrant

    // ---- load input image into LDS (one float4 per thread) ----
    {
        const float4* src4 = (const float4*)(x + (size_t)n_img * 784);
        float4* dst4 = (float4*)img;
        if (t < 196) dst4[t] = src4[t];
    }
    __syncthreads();

    // ---- stage 1: conv1 + pool 3x3 s2 + relu -> h1t[pos][c] bf16, each conv once ----
    {
        const int oy = (q >> 1) * 6, ox = (q & 1) * 6;   // pooled quadrant origin
        const int iy0 = 2 * oy, ix0 = 2 * ox;            // 16B-aligned (28y + {0,12})
        float w[9];
        #pragma unroll
        for (int k = 0; k < 9; ++k) w[k] = w1[c * 9 + k];
        const float bias = b1[c];

        float rows[3][16];                               // ring of 3 input rows (b128)
        {
            const float* s0 = img + iy0 * 28 + ix0;
            const float* s1 = img + (iy0 + 1) * 28 + ix0;
            #pragma unroll
            for (int m = 0; m < 4; ++m) {
                *(float4*)(rows[0] + 4 * m) = *(const float4*)(s0 + 4 * m);
                *(float4*)(rows[1] + 4 * m) = *(const float4*)(s1 + 4 * m);
            }
        }
        float cm[3][6];                                  // colmax ring (3 conv rows)

        #pragma unroll
        for (int r = 0; r < 13; ++r) {                   // conv rows, computed once
            {
                const float* s2 = img + (iy0 + r + 2) * 28 + ix0;
                float* dst = rows[(r + 2) % 3];
                #pragma unroll
                for (int m = 0; m < 4; ++m)
                    *(float4*)(dst + 4 * m) = *(const float4*)(s2 + 4 * m);
            }
            const float* r0 = rows[r % 3];
            const float* r1 = rows[(r + 1) % 3];
            const float* r2 = rows[(r + 2) % 3];
            float a[13];                                 // conv row, branch-free
            #pragma unroll
            for (int xx = 0; xx < 13; ++xx) {
                float v = bias;
                #pragma unroll
                for (int j = 0; j < 3; ++j) {
                    v += r0[xx + j] * w[j];
                    v += r1[xx + j] * w[3 + j];
                    v += r2[xx + j] * w[6 + j];
                }
                a[xx] = v;
            }
            #pragma unroll
            for (int px = 0; px < 6; ++px)               // v_max3
                cm[r % 3][px] = fmaxf(fmaxf(a[2 * px], a[2 * px + 1]), a[2 * px + 2]);
            if (r >= 2 && (r & 1) == 0) {                // pooled row py = r/2 - 1 done
                const int py = r / 2 - 1;
                #pragma unroll
                for (int px = 0; px < 6; ++px) {
                    float m = fmaxf(fmaxf(cm[0][px], cm[1][px]), cm[2][px]);
                    h1t[((oy + py) * 12 + ox + px) * 72 + c] = f2bf(fmaxf(m, 0.0f));
                }
            }
        }
    }
    __syncthreads();

    // ---- stage 2: conv2 MFMA GEMM (16x16x32), M=64, N=100 pad 128, K=576.
    //      Wave wv owns ntiles {2wv, 2wv+1} x ALL 4 mtiles: B read once per block. ----
    const int wv = t >> 6, lane = t & 63;
    const int quad = lane >> 4, mrow = lane & 15;
    {
        int base_el[2];
        #pragma unroll
        for (int nt = 0; nt < 2; ++nt) {
            int n = (wv * 2 + nt) * 16 + mrow;
            if (n > 99) n = 99;                       // pad cols: valid junk, discarded
            int y = n / 10, xx = n - y * 10;
            base_el[nt] = (y * 12 + xx) * 72;
        }
        f32x4 acc[4][2];
        #pragma unroll
        for (int mt = 0; mt < 4; ++mt)
            #pragma unroll
            for (int nt = 0; nt < 2; ++nt) acc[mt][nt] = (f32x4){0.f, 0.f, 0.f, 0.f};

        #pragma unroll
        for (int ks = 0; ks < 18; ++ks) {
            const int s = ks >> 1, h = ks & 1;
            const int ky = s / 3, kx = s - ky * 3;
            const int cinb = h * 32 + quad * 8;
            short8 a[4];
            #pragma unroll
            for (int mt = 0; mt < 4; ++mt)
                a[mt] = *(const short8*)(w2r + s * 4096 + (mt * 16 + mrow) * 64 + cinb);
            const int toff = (ky * 12 + kx) * 72 + cinb;
            #pragma unroll
            for (int nt = 0; nt < 2; ++nt) {
                const short8 b = *(const short8*)(h1t + base_el[nt] + toff);
                #pragma unroll
                for (int mt = 0; mt < 4; ++mt)
                    acc[mt][nt] = __builtin_amdgcn_mfma_f32_16x16x32_bf16(a[mt], b, acc[mt][nt], 0, 0, 0);
            }
        }
        __syncthreads();   // all h1t + img reads done; overlay region reusable
        // epilogue: D[row=quad*4+r][col=mrow] -> cbuf[cout][n] + bias, stride 101
        #pragma unroll
        for (int nt = 0; nt < 2; ++nt) {
            const int n = (wv * 2 + nt) * 16 + mrow;
            if (n < 100) {
                #pragma unroll
                for (int mt = 0; mt < 4; ++mt)
                    #pragma unroll
                    for (int r = 0; r < 4; ++r) {
                        const int co = mt * 16 + quad * 4 + r;
                        cbuf[co * 101 + n] = acc[mt][nt][r] + b2[co];
                    }
            }
        }
    }
    __syncthreads();

    // ---- stage 2b: pool 3x3 s2 + relu -> h2t[pos][cin]; stride 101 => no conflicts ----
    {
        const float* cb = cbuf + c * 101;
        #pragma unroll
        for (int k = 0; k < 4; ++k) {
            const int pos = q * 4 + k;
            const int py = pos >> 2, px = pos & 3;
            float m = -1e30f;
            #pragma unroll
            for (int a = 0; a < 3; ++a)
                #pragma unroll
                for (int b = 0; b < 3; ++b)
                    m = fmaxf(m, cb[(2 * py + a) * 10 + (2 * px + b)]);
            h2t[pos * 64 + c] = fmaxf(m, 0.0f);
        }
    }
    __syncthreads();

    // ---- stage 3: conv3 4x4. Thread (o,g): cins 4g..4g+3 via b128 (2-way = free) ----
    if (t < 160) {
        const int o = t >> 4, g = t & 15;
        const float* w3o = w3 + o * 1024 + g * 64;   // [4 cc][16 pos] contiguous
        float wr[4][16];
        #pragma unroll
        for (int cc = 0; cc < 4; ++cc)
            #pragma unroll
            for (int m = 0; m < 4; ++m)
                *(float4*)(wr[cc] + 4 * m) = *(const float4*)(w3o + cc * 16 + 4 * m);
        float s = 0.0f;
        #pragma unroll
        for (int pos = 0; pos < 16; ++pos) {
            const float4 hv = *(const float4*)(h2t + pos * 64 + g * 4);
            s += hv.x * wr[0][pos] + hv.y * wr[1][pos] + hv.z * wr[2][pos] + hv.w * wr[3][pos];
        }
        prt[t] = s;   // cbuf dead (pool reads barriered above)
    }
    __syncthreads();
    if (t < 10) {
        float s = b3[t];
        #pragma unroll
        for (int g = 0; g < 16; ++g) s += prt[t * 16 + g];
        out[(size_t)n_img * 10 + t] = s;
    }
}

extern "C" void kernel_launch(void* const* d_in, const int* in_sizes, int n_in,
                              void* d_out, int out_size, void* d_ws, size_t ws_size,
                              hipStream_t stream) {
    const float* x  = (const float*)d_in[0];
    const float* w1 = (const float*)d_in[1];
    const float* b1 = (const float*)d_in[2];
    const float* w2 = (const float*)d_in[3];
    const float* b2 = (const float*)d_in[4];
    const float* w3 = (const float*)d_in[5];
    const float* b3 = (const float*)d_in[6];
    float* out = (float*)d_out;
    short* w2r = (short*)d_ws;            // 36864 bf16 = 73728 B

    const int B = in_sizes[0] / 784;      // 2048
    prep_w2<<<144, 256, 0, stream>>>(w2, w2r);
    convnet_fused<<<B, 256, 0, stream>>>(x, w1, b1, w2r, b2, w3, b3, out);
}

// Round 8
// 124.715 us; speedup vs baseline: 1.2397x; 1.2397x over previous
//
#include <hip/hip_runtime.h>

// R8 = R6 + A-fragments preloaded into registers at kernel start (before stage 1),
// so the stage-2 K-loop has ZERO VMEM operations — pure ds_read_b128 + MFMA.
// R4/R5/R7 all proved divergent global A-loads inside the K-loop are latency death;
// R8 hides their latency behind stage-1 compute instead.
// Cost: ~72 extra VGPRs held through stage 1 -> ~3 blocks/CU (was 5).
// LDS 29952 B.

typedef __attribute__((ext_vector_type(8))) short short8;   // 8 x bf16 (4 VGPRs)
typedef __attribute__((ext_vector_type(4))) float f32x4;

__device__ inline short f2bf(float f) {   // fp32 -> bf16, round-to-nearest-even
    union { float f; unsigned u; } v; v.f = f;
    unsigned r = (v.u + 0x7FFFu + ((v.u >> 16) & 1u)) >> 16;
    return (short)r;
}

// w2r[s][cout][cin] (bf16), s = ky*3+kx: MFMA A-fragments contiguous in cin.
__global__ __launch_bounds__(256) void prep_w2(const float* __restrict__ w2,
                                               short* __restrict__ w2r) {
    int i = blockIdx.x * 256 + threadIdx.x;      // 9*64*64 = 36864
    if (i >= 36864) return;
    int s = i >> 12, cout = (i >> 6) & 63, cin = i & 63;
    w2r[i] = f2bf(w2[cout * 576 + cin * 9 + s]);
}

__global__ __launch_bounds__(256) void convnet_fused(
    const float* __restrict__ x,   // [B,1,28,28]
    const float* __restrict__ w1,  // [64,1,3,3]
    const float* __restrict__ b1,  // [64]
    const short* __restrict__ w2r, // [9][64][64] bf16
    const float* __restrict__ b2,  // [64]
    const float* __restrict__ w3,  // [10,64,4,4]
    const float* __restrict__ b3,  // [10]
    float* __restrict__ out)       // [B,10]
{
    // Overlays (floats):
    //   [0..5184)    h1t bf16 [144 pos][72]    }-> cbuf fp32 [64][101] = [0..6464)
    //   [5184..5968) img 28x28                 }   (h1t & img dead by cbuf write)
    //   [6464..7488) h2t fp32 [16 pos][64 cin]
    //   [0..160)     stage-3 partials (cbuf dead)
    __shared__ float lds_f[7488];                // 29952 B
    short* h1t  = (short*)lds_f;
    float* img  = lds_f + 5184;
    float* cbuf = lds_f;
    float* h2t  = lds_f + 6464;
    float* prt  = lds_f;

    const int n_img = blockIdx.x;
    const int t = threadIdx.x;
    const int c = t >> 2;        // 0..63
    const int q = t & 3;         // quadrant
    const int wv = t >> 6, lane = t & 63;
    const int quad = lane >> 4, mrow = lane & 15;

    // ---- A-fragment preload: 18 x short8, issued FIRST; latency hidden by stage 1 ----
    short8 areg[18];
    #pragma unroll
    for (int ks = 0; ks < 18; ++ks) {
        const int s = ks >> 1, h = ks & 1;
        areg[ks] = *(const short8*)(w2r + s * 4096 + (wv * 16 + mrow) * 64
                                    + h * 32 + quad * 8);
    }

    // ---- load input image into LDS (one float4 per thread) ----
    {
        const float4* src4 = (const float4*)(x + (size_t)n_img * 784);
        float4* dst4 = (float4*)img;
        if (t < 196) dst4[t] = src4[t];
    }
    __syncthreads();

    // ---- stage 1: conv1 + pool 3x3 s2 + relu -> h1t[pos][c] bf16, each conv once ----
    {
        const int oy = (q >> 1) * 6, ox = (q & 1) * 6;   // pooled quadrant origin
        const int iy0 = 2 * oy, ix0 = 2 * ox;            // 16B-aligned (28y + {0,12})
        float w[9];
        #pragma unroll
        for (int k = 0; k < 9; ++k) w[k] = w1[c * 9 + k];
        const float bias = b1[c];

        float rows[3][16];                               // ring of 3 input rows (b128)
        {
            const float* s0 = img + iy0 * 28 + ix0;
            const float* s1 = img + (iy0 + 1) * 28 + ix0;
            #pragma unroll
            for (int m = 0; m < 4; ++m) {
                *(float4*)(rows[0] + 4 * m) = *(const float4*)(s0 + 4 * m);
                *(float4*)(rows[1] + 4 * m) = *(const float4*)(s1 + 4 * m);
            }
        }
        float cm[3][6];                                  // colmax ring (3 conv rows)

        #pragma unroll
        for (int r = 0; r < 13; ++r) {                   // conv rows, computed once
            {
                const float* s2 = img + (iy0 + r + 2) * 28 + ix0;
                float* dst = rows[(r + 2) % 3];
                #pragma unroll
                for (int m = 0; m < 4; ++m)
                    *(float4*)(dst + 4 * m) = *(const float4*)(s2 + 4 * m);
            }
            const float* r0 = rows[r % 3];
            const float* r1 = rows[(r + 1) % 3];
            const float* r2 = rows[(r + 2) % 3];
            float a[13];
            #pragma unroll
            for (int xx = 0; xx < 13; ++xx) {
                float v = bias;
                #pragma unroll
                for (int j = 0; j < 3; ++j) {
                    v += r0[xx + j] * w[j];
                    v += r1[xx + j] * w[3 + j];
                    v += r2[xx + j] * w[6 + j];
                }
                a[xx] = v;
            }
            #pragma unroll
            for (int px = 0; px < 6; ++px)               // v_max3
                cm[r % 3][px] = fmaxf(fmaxf(a[2 * px], a[2 * px + 1]), a[2 * px + 2]);
            if (r >= 2 && (r & 1) == 0) {                // pooled row py = r/2 - 1 done
                const int py = r / 2 - 1;
                #pragma unroll
                for (int px = 0; px < 6; ++px) {
                    float m = fmaxf(fmaxf(cm[0][px], cm[1][px]), cm[2][px]);
                    h1t[((oy + py) * 12 + ox + px) * 72 + c] = f2bf(fmaxf(m, 0.0f));
                }
            }
        }
    }
    __syncthreads();

    // ---- stage 2: conv2 MFMA GEMM (16x16x32), M=64, N=100 pad 112, K=576.
    //      Wave wv owns mtile wv, all 7 ntiles. A in registers; K-loop is LDS+MFMA only. ----
    {
        int base_el[7];
        #pragma unroll
        for (int nt = 0; nt < 7; ++nt) {
            int n = nt * 16 + mrow; if (n > 99) n = 99;   // pad cols: valid junk, discarded
            int y = n / 10, xx = n - y * 10;
            base_el[nt] = (y * 12 + xx) * 72;
        }
        f32x4 acc[7];
        #pragma unroll
        for (int nt = 0; nt < 7; ++nt) acc[nt] = (f32x4){0.f, 0.f, 0.f, 0.f};

        #pragma unroll
        for (int ks = 0; ks < 18; ++ks) {
            const int s = ks >> 1, h = ks & 1;
            const int ky = s / 3, kx = s - ky * 3;
            const int toff = (ky * 12 + kx) * 72 + h * 32 + quad * 8;
            #pragma unroll
            for (int nt = 0; nt < 7; ++nt) {
                const short8 b = *(const short8*)(h1t + base_el[nt] + toff);
                acc[nt] = __builtin_amdgcn_mfma_f32_16x16x32_bf16(areg[ks], b, acc[nt], 0, 0, 0);
            }
        }
        __syncthreads();   // all h1t + img reads done; overlay region reusable
        // epilogue: D[row=quad*4+r][col=mrow] -> cbuf[cout][n] + bias, stride 101
        #pragma unroll
        for (int nt = 0; nt < 7; ++nt) {
            const int n = nt * 16 + mrow;
            if (n < 100) {
                #pragma unroll
                for (int r = 0; r < 4; ++r) {
                    const int co = wv * 16 + quad * 4 + r;
                    cbuf[co * 101 + n] = acc[nt][r] + b2[co];
                }
            }
        }
    }
    __syncthreads();

    // ---- stage 2b: pool 3x3 s2 + relu -> h2t[pos][cin]; stride 101 => no conflicts ----
    {
        const float* cb = cbuf + c * 101;
        #pragma unroll
        for (int k = 0; k < 4; ++k) {
            const int pos = q * 4 + k;
            const int py = pos >> 2, px = pos & 3;
            float m = -1e30f;
            #pragma unroll
            for (int a = 0; a < 3; ++a)
                #pragma unroll
                for (int b = 0; b < 3; ++b)
                    m = fmaxf(m, cb[(2 * py + a) * 10 + (2 * px + b)]);
            h2t[pos * 64 + c] = fmaxf(m, 0.0f);
        }
    }
    __syncthreads();

    // ---- stage 3: conv3 4x4. Thread (o,g): cins 4g..4g+3 via b128 (2-way = free) ----
    if (t < 160) {
        const int o = t >> 4, g = t & 15;
        const float* w3o = w3 + o * 1024 + g * 64;   // [4 cc][16 pos] contiguous
        float wr[4][16];
        #pragma unroll
        for (int cc = 0; cc < 4; ++cc)
            #pragma unroll
            for (int m = 0; m < 4; ++m)
                *(float4*)(wr[cc] + 4 * m) = *(const float4*)(w3o + cc * 16 + 4 * m);
        float s = 0.0f;
        #pragma unroll
        for (int pos = 0; pos < 16; ++pos) {
            const float4 hv = *(const float4*)(h2t + pos * 64 + g * 4);
            s += hv.x * wr[0][pos] + hv.y * wr[1][pos] + hv.z * wr[2][pos] + hv.w * wr[3][pos];
        }
        prt[t] = s;   // cbuf dead (pool reads barriered above)
    }
    __syncthreads();
    if (t < 10) {
        float s = b3[t];
        #pragma unroll
        for (int g = 0; g < 16; ++g) s += prt[t * 16 + g];
        out[(size_t)n_img * 10 + t] = s;
    }
}

extern "C" void kernel_launch(void* const* d_in, const int* in_sizes, int n_in,
                              void* d_out, int out_size, void* d_ws, size_t ws_size,
                              hipStream_t stream) {
    const float* x  = (const float*)d_in[0];
    const float* w1 = (const float*)d_in[1];
    const float* b1 = (const float*)d_in[2];
    const float* w2 = (const float*)d_in[3];
    const float* b2 = (const float*)d_in[4];
    const float* w3 = (const float*)d_in[5];
    const float* b3 = (const float*)d_in[6];
    float* out = (float*)d_out;
    short* w2r = (short*)d_ws;            // 36864 bf16 = 73728 B

    const int B = in_sizes[0] / 784;      // 2048
    prep_w2<<<144, 256, 0, stream>>>(w2, w2r);
    convnet_fused<<<B, 256, 0, stream>>>(x, w1, b1, w2r, b2, w3, b3, out);
}